// Round 1
// baseline (1056.964 us; speedup 1.0000x reference)
//
#include <hip/hip_runtime.h>

// Local_Layer (GAT-style): per node n, per head h:
//   score[m,h] = relu( q[n,h,:]·W[h,0:16] + k[n,m,h,:]·W[h,16:32] + b[h] )
//   attn = softmax_m(score);  out[n,h*16+d] = sum_m attn[m,h]*s[n,m,h*16+d]
//
// N=50000, M=32, H=8, D=16, HID=128. All f32.
// HBM-bound: s is 819 MB, read exactly once. v2: PERSISTENT blocks with
// cross-node register prefetch — load node n+G while computing node n, so
// the HBM pipe never drains during the compute/barrier tail. One-shot
// blocks (v1) paid ~900cy cold-start latency 50000 times, un-overlapped.

#define MM   32
#define HH   8
#define DD   16
#define HIDC 128
#define SROW 129   // odd stride: pass-A (stride-16 per lane) and pass-B
                   // (lane-consecutive) LDS reads both conflict-free
#define GRID 1024  // 4 blocks/CU * 256 CUs; grid-stride over nodes

__global__ __launch_bounds__(256, 4)
void gat_kernel(const float* __restrict__ hq,   // [N,128] query features
                const float* __restrict__ s,    // [N,32,128] neighbor K=V
                const float* __restrict__ W,    // [8,32]
                const float* __restrict__ b,    // [8]
                float* __restrict__ out,        // [N,128]
                int N)
{
    __shared__ float s_tile[MM * SROW];   // 16512 B
    __shared__ float qdot_sh[HH];         // per-head q·Wq + b
    __shared__ float attn_sh[MM * 9];     // stride 9: conflict-free write

    const int t  = threadIdx.x;
    const int mA = t & 31;   // pass-A neighbor index
    const int hA = t >> 5;   // pass-A head index
    const int G  = gridDim.x;

    // ---- per-thread constants, loaded ONCE per persistent block ----
    float wk[16];            // my pass-A head's key weights (16 VGPRs)
    {
        const float4* wg = reinterpret_cast<const float4*>(W + hA * 32 + 16);
#pragma unroll
        for (int j = 0; j < 4; ++j) {
            float4 w4 = wg[j];
            wk[4 * j + 0] = w4.x; wk[4 * j + 1] = w4.y;
            wk[4 * j + 2] = w4.z; wk[4 * j + 3] = w4.w;
        }
    }
    // qdot lane constants (used by threads 0..127)
    const int   qh = (t & 127) >> 4;
    const int   qe = t & 15;
    const float wq = W[qh * 32 + qe];
    const float bh = b[qh];

    int n = blockIdx.x;
    if (n >= N) return;      // grid is clamped to N, so no partial blocks

    // ---- prologue: load node n into registers ----
    float4 v[4];
    float  qv = 0.f;
    {
        const float4* sg = reinterpret_cast<const float4*>(s + (size_t)n * (MM * HIDC));
#pragma unroll
        for (int j = 0; j < 4; ++j) v[j] = sg[t + 256 * j];
        if (t < HIDC) qv = hq[(size_t)n * HIDC + t];
    }

    while (true) {
        const int next = n + G;

        // ---- prefetch node n+G (no wait: vmcnt lands at the swap below,
        //      i.e. after pass B — latency hidden under this node's work) --
        float4 vn[4];
        float  qvn = 0.f;
        if (next < N) {
            const float4* sg = reinterpret_cast<const float4*>(s + (size_t)next * (MM * HIDC));
#pragma unroll
            for (int j = 0; j < 4; ++j) vn[j] = sg[t + 256 * j];
            if (t < HIDC) qvn = hq[(size_t)next * HIDC + t];
        }

        // ---- stage current tile: scalar b32 LDS writes (odd stride breaks
        //      b128 alignment); 4-way write conflict accepted — reads (2x
        //      the write traffic) stay conflict-free with SROW=129. ----
#pragma unroll
        for (int j = 0; j < 4; ++j) {
            int idx = t + 256 * j;          // float4 index within the tile
            int m = idx >> 5;               // row (neighbor)
            int c = (idx & 31) << 2;        // column (channel)
            float* dst = &s_tile[m * SROW + c];
            dst[0] = v[j].x; dst[1] = v[j].y; dst[2] = v[j].z; dst[3] = v[j].w;
        }

        // ---- qdot[h] = q·W[h,0:16] + b[h]; 16-lane shuffle reduction ----
        if (t < HIDC) {
            float p = qv * wq;
#pragma unroll
            for (int off = 8; off; off >>= 1) p += __shfl_xor(p, off, 16);
            if (qe == 0) qdot_sh[qh] = p + bh;
        }

        __syncthreads();   // B1: s_tile + qdot_sh visible

        // ---- pass A: score + softmax over m (32-lane groups == m) ----
        {
            float kdot = 0.f;
            const float* srow = &s_tile[mA * SROW + hA * DD];
#pragma unroll
            for (int e = 0; e < 16; ++e) kdot += srow[e] * wk[e];
            float score = fmaxf(kdot + qdot_sh[hA], 0.f);   // relu

            float mx = score;
#pragma unroll
            for (int off = 16; off; off >>= 1) mx = fmaxf(mx, __shfl_xor(mx, off, 32));
            float es = __expf(score - mx);
            float sum = es;
#pragma unroll
            for (int off = 16; off; off >>= 1) sum += __shfl_xor(sum, off, 32);

            attn_sh[mA * 9 + hA] = es / sum;
        }

        __syncthreads();   // B2: attn_sh visible

        // ---- pass B: out[c] = sum_m attn[m, c/16] * s_tile[m, c] ----
        if (t < HIDC) {
            const int hB = t >> 4;
            float acc = 0.f;
#pragma unroll 8
            for (int m = 0; m < MM; ++m)
                acc += attn_sh[m * 9 + hB] * s_tile[m * SROW + t];
            out[(size_t)n * HIDC + t] = acc;
        }

        if (next >= N) break;

        __syncthreads();   // B3: s_tile free for next iteration's staging

        n = next;
#pragma unroll
        for (int j = 0; j < 4; ++j) v[j] = vn[j];   // vmcnt(0) waits HERE
        qv = qvn;
    }
}

extern "C" void kernel_launch(void* const* d_in, const int* in_sizes, int n_in,
                              void* d_out, int out_size, void* d_ws, size_t ws_size,
                              hipStream_t stream) {
    const float* hq = (const float*)d_in[0];   // [N,128]
    const float* s  = (const float*)d_in[1];   // [N,32,128]
    const float* W  = (const float*)d_in[2];   // [8,32]
    const float* b  = (const float*)d_in[3];   // [8]
    float* out = (float*)d_out;

    const int N = in_sizes[0] / HIDC;          // 50000
    const int grid = GRID < N ? GRID : N;
    gat_kernel<<<dim3(grid), dim3(256), 0, stream>>>(hq, s, W, b, out, N);
}